// Round 3
// baseline (129.218 us; speedup 1.0000x reference)
//
#include <hip/hip_runtime.h>
#include <hip/hip_bf16.h>

typedef unsigned char u8;
typedef unsigned short u16;
typedef unsigned int u32;
typedef float f32x16 __attribute__((ext_vector_type(16)));
typedef float f32x2 __attribute__((ext_vector_type(2)));
typedef int i32x4 __attribute__((ext_vector_type(4)));
typedef int i32x8 __attribute__((ext_vector_type(8)));

#define B_SZ 8192
#define D_SZ 768
#define TAU_INV 10.0f
// elements scaled by 32 -> logits scaled by 1024; exp2 const = log2(e)*10/1024
#define ESCALE 0.014088818758681283f
#define FP4_SCALE 32.0f
// Schraudolph fast-exp2: e = as_float((int)(x*K1 + K2)), K1 = ESCALE*2^23,
// K2 = 127*2^23 - sigma, sigma = 0.05645*2^23 (mean-zero error for sums)
#define SCHRAU_K1 118185.58f
#define SCHRAU_K2 1064879685.0f

// FP4 tiled operand layout: tile = 32 rows x 64 k-elems x 0.5 B = 1024 B,
// tiles indexed (rowgroup rg = row>>5) * 12 + (kblock kb = k>>6).
// Within a tile, byte for (row r, k) at  h*512 + (r&31)*16 + ((k&31)>>1),
// nibble = k&1 (low nibble = even k), where h=(k>>5)&1.
// Consequence: an MFMA fragment read is ONE coalesced dwordx4 at base+lane*16,
// and a tile stages into LDS with ONE global_load_lds (64 lanes x 16 B, linear).

// fp32 -> e2m1 nibble, round-to-nearest (values 0,.5,1,1.5,2,3,4,6; clamp at 6)
__device__ __forceinline__ u32 fp4_enc(float x) {
    float y = fabsf(x);
    u32 n = (u32)(y >= 0.25f) + (u32)(y >= 0.75f) + (u32)(y >= 1.25f) +
            (u32)(y >= 1.75f) + (u32)(y >= 2.5f)  + (u32)(y >= 3.5f) +
            (u32)(y >= 5.0f);
    return n | (x < 0.f ? 8u : 0u);
}

__device__ __forceinline__ u16 fp4_pack4(float x, float y, float z, float w) {
    return (u16)(fp4_enc(x) | (fp4_enc(y) << 4) | (fp4_enc(z) << 8) | (fp4_enc(w) << 12));
}

// ---------------- Kernel 1: row norms, fp4 normalize (x32), tiled store, fp32 diag ----------
__global__ __launch_bounds__(256) void norm_kernel(const float4* __restrict__ v,
                                                   const float4* __restrict__ u,
                                                   u16* __restrict__ vn,
                                                   u16* __restrict__ un,
                                                   float* __restrict__ diag) {
    const int wid = threadIdx.x >> 6, lane = threadIdx.x & 63;
    const int row = blockIdx.x * 4 + wid;
    const float4* vr = v + (size_t)row * 192;
    const float4* ur = u + (size_t)row * 192;
    float4 a[3], b[3];
    float sv = 0.f, su = 0.f, sd = 0.f;
#pragma unroll
    for (int c = 0; c < 3; ++c) {
        a[c] = vr[lane + 64 * c];
        b[c] = ur[lane + 64 * c];
        sv += a[c].x * a[c].x + a[c].y * a[c].y + a[c].z * a[c].z + a[c].w * a[c].w;
        su += b[c].x * b[c].x + b[c].y * b[c].y + b[c].z * b[c].z + b[c].w * b[c].w;
        sd += a[c].x * b[c].x + a[c].y * b[c].y + a[c].z * b[c].z + a[c].w * b[c].w;
    }
#pragma unroll
    for (int m = 1; m < 64; m <<= 1) {
        sv += __shfl_xor(sv, m);
        su += __shfl_xor(su, m);
        sd += __shfl_xor(sd, m);
    }
    const float iv = FP4_SCALE / fmaxf(sqrtf(sv), 1e-8f);
    const float iu = FP4_SCALE / fmaxf(sqrtf(su), 1e-8f);
    const int rg = row >> 5, rr = row & 31;
#pragma unroll
    for (int c = 0; c < 3; ++c) {
        u16 pa = fp4_pack4(a[c].x * iv, a[c].y * iv, a[c].z * iv, a[c].w * iv);
        u16 pb = fp4_pack4(b[c].x * iu, b[c].y * iu, b[c].z * iu, b[c].w * iu);
        const int e = lane + 64 * c;   // float4 index within the row (k = 4e..4e+3)
        // u16 index: tile*(1024/2) + h*256 + rr*8 + (e&7)
        const int idx = (rg * 12 + (e >> 4)) * 512 + ((e >> 3) & 1) * 256 + rr * 8 + (e & 7);
        vn[idx] = pa;
        un[idx] = pb;
    }
    if (lane == 0) diag[row] = sd * iv * iu * TAU_INV / (FP4_SCALE * FP4_SCALE);
}

// LDS fragment read: ONE ds_read_b128; fp4 MFMA (cbsz=4/blgp=4) reads only
// v[0:3] of the 8-reg operand; upper half left UNDEF.
__device__ __forceinline__ i32x8 ldsfrag(const u8* p) {
    i32x4 lo = *(const i32x4*)p;
    return __builtin_shufflevector(lo, lo, 0, 1, 2, 3, -1, -1, -1, -1);
}

__device__ __forceinline__ void gload_lds16(const u8* g, u8* l) {
    __builtin_amdgcn_global_load_lds((const __attribute__((address_space(1))) void*)g,
                                     (__attribute__((address_space(3))) void*)l, 16, 0, 0);
}

__device__ __forceinline__ f32x16 mx_mfma4(i32x8 a, i32x8 b, f32x16 c) {
    // cbsz=4 (A fmt E2M1), blgp=4 (B fmt E2M1), scales = 127 -> 1.0
    return __builtin_amdgcn_mfma_scale_f32_32x32x64_f8f6f4(
        a, b, c, 4, 4, 0, 0x7F7F7F7F, 0, 0x7F7F7F7F);
}

// ------- Kernel 2: 256x256 fp4 MX MFMA block tile, 8 waves (512 thr), HK geometry:
//         2x4 wave grid, 128x64 per wave (4x2 register blocking -> 768 B LDS read
//         per MFMA, LDS pipe ~= matrix pipe). BK=128 K-steps: 6 steps, 6 barriers.
//         3-slot LDS staging (96 KB) via global_load_lds, depth-2 prefetch,
//         counted s_waitcnt vmcnt(4); setprio around MFMA; packed-f32
//         Schraudolph epilogue with dual fold-reduce -------
__global__ __launch_bounds__(512, 2) void simexp_kernel(const u8* __restrict__ vn,
                                                        const u8* __restrict__ un,
                                                        float* __restrict__ rowP,
                                                        float* __restrict__ colP) {
    // [slot][rowgroup-slot: 0-7 = A, 8-15 = B][kblock 0-1][1024 B]
    __shared__ __attribute__((aligned(16))) u8 stg[3][16][2][1024];   // 96 KB
    __shared__ float rowLds[4][256];                                   // 4 KB
    __shared__ float colLds[2][256];                                   // 2 KB

    const int tid  = threadIdx.x;
    const int w    = tid >> 6;       // wave 0..7
    const int lane = tid & 63;
    const int l32  = lane & 31;
    const int h    = lane >> 5;
    const int wr = w >> 2, wc = w & 3;   // 2x4 wave grid, 128x64 tile each

    // 1024 blocks = 16 chunks of 64 (8rb x 8cb) for L2 locality
    const int id = blockIdx.x;
    const int chunk = id >> 6;
    const int li = id & 63;
    const int rb = ((chunk >> 2) << 3) + (li >> 3);   // 0..31
    const int cb = ((chunk & 3) << 3) + (li & 7);     // 0..31

    // staging: wave w stages A rowgroup rb*8+w and B rowgroup cb*8+w, the two
    // kblocks of the current BK=128 step (4 x 1 KB global_load_lds per step).
    const u8* gA = vn + (size_t)(rb * 8 + w) * 12288 + (u32)lane * 16;
    const u8* gB = un + (size_t)(cb * 8 + w) * 12288 + (u32)lane * 16;

    f32x16 acc[4][2];
#pragma unroll
    for (int i = 0; i < 4; ++i)
#pragma unroll
        for (int j = 0; j < 2; ++j)
#pragma unroll
            for (int r = 0; r < 16; ++r) acc[i][j][r] = 0.f;

#define STAGE(t)                                                  \
    {                                                             \
        gload_lds16(gA + (2 * (t)) * 1024,     &stg[(t) % 3][w][0][0]);     \
        gload_lds16(gA + (2 * (t) + 1) * 1024, &stg[(t) % 3][w][1][0]);     \
        gload_lds16(gB + (2 * (t)) * 1024,     &stg[(t) % 3][8 + w][0][0]); \
        gload_lds16(gB + (2 * (t) + 1) * 1024, &stg[(t) % 3][8 + w][1][0]); \
    }

    // prologue: prefetch K-steps 0 and 1 (8 loads out; wait own step-0 4 done)
    STAGE(0)
    STAGE(1)
    asm volatile("s_waitcnt vmcnt(4)\n\ts_barrier" ::: "memory");

#pragma unroll
    for (int t = 0; t < 6; ++t) {
        if (t + 2 < 6) STAGE(t + 2)          // prefetch depth 2 into slot (t+2)%3
        const u8* s = &stg[t % 3][0][0][0] + (u32)lane * 16;
#pragma unroll
        for (int kk = 0; kk < 2; ++kk) {
            i32x8 fa0 = ldsfrag(s + ((wr * 4 + 0) * 2 + kk) * 1024);
            i32x8 fa1 = ldsfrag(s + ((wr * 4 + 1) * 2 + kk) * 1024);
            i32x8 fa2 = ldsfrag(s + ((wr * 4 + 2) * 2 + kk) * 1024);
            i32x8 fa3 = ldsfrag(s + ((wr * 4 + 3) * 2 + kk) * 1024);
            i32x8 fb0 = ldsfrag(s + ((8 + wc * 2 + 0) * 2 + kk) * 1024);
            i32x8 fb1 = ldsfrag(s + ((8 + wc * 2 + 1) * 2 + kk) * 1024);
            __builtin_amdgcn_s_setprio(1);
            acc[0][0] = mx_mfma4(fa0, fb0, acc[0][0]);
            acc[1][0] = mx_mfma4(fa1, fb0, acc[1][0]);
            acc[2][0] = mx_mfma4(fa2, fb0, acc[2][0]);
            acc[3][0] = mx_mfma4(fa3, fb0, acc[3][0]);
            acc[0][1] = mx_mfma4(fa0, fb1, acc[0][1]);
            acc[1][1] = mx_mfma4(fa1, fb1, acc[1][1]);
            acc[2][1] = mx_mfma4(fa2, fb1, acc[2][1]);
            acc[3][1] = mx_mfma4(fa3, fb1, acc[3][1]);
            __builtin_amdgcn_s_setprio(0);
        }
        // own prefetch for step t+1 must be done (4 newest, for t+2, may fly),
        // then barrier so ALL waves' tiles for t+1 are visible. t=4 drains its
        // last prefetch (step 5). No sync after t=5 (stg never reused; epilogue
        // has its own __syncthreads before cross-wave LDS reads).
        if (t < 4)       asm volatile("s_waitcnt vmcnt(4)\n\ts_barrier" ::: "memory");
        else if (t == 4) asm volatile("s_waitcnt vmcnt(0)\n\ts_barrier" ::: "memory");
    }
#undef STAGE

    // ---------------- Epilogue ----------------
    // 32x32 C/D layout: col = lane&31, row = (reg&3) + 8*(reg>>2) + 4*h.
    // Packed Schraudolph exp; two fold-reduces (i-blocks {0,1} and {2,3}).
    f32x2 va[16], vb[16];      // row-sum partials (pairs of regs)
    f32x2 cacc2[2];            // col-sum partials
#pragma unroll
    for (int p = 0; p < 16; ++p) {
        va[p].x = 0.f; va[p].y = 0.f;
        vb[p].x = 0.f; vb[p].y = 0.f;
    }
    cacc2[0].x = 0.f; cacc2[0].y = 0.f;
    cacc2[1].x = 0.f; cacc2[1].y = 0.f;
#pragma unroll
    for (int i = 0; i < 4; ++i)
#pragma unroll
        for (int j = 0; j < 2; ++j)
#pragma unroll
            for (int r = 0; r < 16; r += 2) {
                f32x2 a;
                a.x = acc[i][j][r];
                a.y = acc[i][j][r + 1];
                f32x2 t = a * SCHRAU_K1 + SCHRAU_K2;   // v_pk_fma_f32
                f32x2 e;
                e.x = __int_as_float((int)t.x);
                e.y = __int_as_float((int)t.y);
                if (i < 2) va[(i & 1) * 8 + (r >> 1)] += e;
                else       vb[(i & 1) * 8 + (r >> 1)] += e;
                cacc2[j] += e;
            }

    // Fold-reduce over the 32 columns: each lane ends owning one row total per fold.
#pragma unroll
    for (int m = 16; m >= 2; m >>= 1) {
        const int n = m >> 1;
        const bool hi = (l32 & m) != 0;
#pragma unroll
        for (int p = 0; p < n; ++p) {
            {
                f32x2 a = va[p], b = va[p + n];
                f32x2 x, y;
                x.x = hi ? b.x : a.x;  x.y = hi ? b.y : a.y;
                y.x = hi ? a.x : b.x;  y.y = hi ? a.y : b.y;
                f32x2 s;
                s.x = __shfl_xor(y.x, m);
                s.y = __shfl_xor(y.y, m);
                va[p] = x + s;
            }
            {
                f32x2 a = vb[p], b = vb[p + n];
                f32x2 x, y;
                x.x = hi ? b.x : a.x;  x.y = hi ? b.y : a.y;
                y.x = hi ? a.x : b.x;  y.y = hi ? a.y : b.y;
                f32x2 s;
                s.x = __shfl_xor(y.x, m);
                s.y = __shfl_xor(y.y, m);
                vb[p] = x + s;
            }
        }
    }
    {   // lanes l and l^1 hold complementary 16-lane partials of the same pair
        f32x2 s;
        s.x = __shfl_xor(va[0].x, 1);
        s.y = __shfl_xor(va[0].y, 1);
        va[0] += s;
        s.x = __shfl_xor(vb[0].x, 1);
        s.y = __shfl_xor(vb[0].y, 1);
        vb[0] += s;
    }
    {
        const int q = (l32 >> 1) & 15;
        const int tt = 2 * q + (l32 & 1);
        const int i2 = tt >> 4, r2 = tt & 15;
        const int rbase = i2 * 32 + (r2 & 3) + 8 * (r2 >> 2) + 4 * h;
        rowLds[wc][wr * 128 + rbase]      = (l32 & 1) ? va[0].y : va[0].x;
        rowLds[wc][wr * 128 + 64 + rbase] = (l32 & 1) ? vb[0].y : vb[0].x;
    }
    {
        float c0 = cacc2[0].x + cacc2[0].y;
        float c1 = cacc2[1].x + cacc2[1].y;
        c0 += __shfl_xor(c0, 32);
        c1 += __shfl_xor(c1, 32);
        if (h == 0) {
            colLds[wr][wc * 64 + l32]      = c0;
            colLds[wr][wc * 64 + 32 + l32] = c1;
        }
    }
    __syncthreads();
    if (tid < 256) {
        rowP[(size_t)cb * B_SZ + rb * 256 + tid] =
            rowLds[0][tid] + rowLds[1][tid] + rowLds[2][tid] + rowLds[3][tid];
    } else {
        const int t = tid - 256;
        colP[(size_t)rb * B_SZ + cb * 256 + t] = colLds[0][t] + colLds[1][t];
    }
}

// ---------------- Kernel 3: reduce partials, log, subtract diag, mean ----------------
__global__ __launch_bounds__(256) void finalize_kernel(const float* __restrict__ rowP,
                                                       const float* __restrict__ colP,
                                                       const float* __restrict__ diag,
                                                       float* __restrict__ out) {
    const int i = blockIdx.x * 256 + threadIdx.x;
    float rs = 0.f, cs = 0.f;
#pragma unroll 8
    for (int p = 0; p < 32; ++p) {
        rs += rowP[(size_t)p * B_SZ + i];
        cs += colP[(size_t)p * B_SZ + i];
    }
    float contrib = (0.75f * logf(rs) + 0.25f * logf(cs) - diag[i]) * (1.0f / (float)B_SZ);
#pragma unroll
    for (int m = 1; m < 64; m <<= 1) contrib += __shfl_xor(contrib, m);
    __shared__ float red[4];
    const int wid = threadIdx.x >> 6, lane = threadIdx.x & 63;
    if (lane == 0) red[wid] = contrib;
    __syncthreads();
    if (threadIdx.x == 0) atomicAdd(out, red[0] + red[1] + red[2] + red[3]);
}

extern "C" void kernel_launch(void* const* d_in, const int* in_sizes, int n_in,
                              void* d_out, int out_size, void* d_ws, size_t ws_size,
                              hipStream_t stream) {
    const float* v = (const float*)d_in[0];
    const float* u = (const float*)d_in[1];
    char* ws = (char*)d_ws;
    // workspace layout (~8.4 MB)
    u16* vn4   = (u16*)(ws);                    // 8192*384 B  = 3,145,728
    u16* un4   = (u16*)(ws + 3145728);          // 3,145,728
    float* dg  = (float*)(ws + 6291456);        // 8192*4      = 32,768
    float* rwp = (float*)(ws + 6324224);        // 32*8192*4   = 1,048,576
    float* clp = (float*)(ws + 7372800);        // 1,048,576
    float* out = (float*)d_out;

    hipMemsetAsync(out, 0, sizeof(float), stream);
    hipLaunchKernelGGL(norm_kernel, dim3(2048), dim3(256), 0, stream,
                       (const float4*)v, (const float4*)u, vn4, un4, dg);
    hipLaunchKernelGGL(simexp_kernel, dim3(1024), dim3(512), 0, stream,
                       (const u8*)vn4, (const u8*)un4, rwp, clp);
    hipLaunchKernelGGL(finalize_kernel, dim3(B_SZ / 256), dim3(256), 0, stream, rwp, clp, dg, out);
}

// Round 4
// 128.204 us; speedup vs baseline: 1.0079x; 1.0079x over previous
//
#include <hip/hip_runtime.h>
#include <hip/hip_bf16.h>

typedef unsigned char u8;
typedef unsigned short u16;
typedef unsigned int u32;
typedef float f32x16 __attribute__((ext_vector_type(16)));
typedef float f32x2 __attribute__((ext_vector_type(2)));
typedef int i32x4 __attribute__((ext_vector_type(4)));
typedef int i32x8 __attribute__((ext_vector_type(8)));

#define B_SZ 8192
#define D_SZ 768
#define TAU_INV 10.0f
// elements scaled by 32 -> logits scaled by 1024; exp2 const = log2(e)*10/1024
#define ESCALE 0.014088818758681283f
#define FP4_SCALE 32.0f
// Schraudolph fast-exp2: e = as_float((int)(x*K1 + K2)), K1 = ESCALE*2^23,
// K2 = 127*2^23 - sigma, sigma = 0.05645*2^23 (mean-zero error for sums)
#define SCHRAU_K1 118185.58f
#define SCHRAU_K2 1064879685.0f

// FP4 tiled operand layout: tile = 32 rows x 64 k-elems x 0.5 B = 1024 B,
// tiles indexed (rowgroup rg = row>>5) * 12 + (kblock kb = k>>6).
// Within a tile, byte for (row r, k) at  h*512 + (r&31)*16 + ((k&31)>>1),
// nibble = k&1 (low nibble = even k), where h=(k>>5)&1.
// Consequence: an MFMA fragment read is ONE coalesced dwordx4 at base+lane*16,
// and a tile stages into LDS with ONE global_load_lds (64 lanes x 16 B, linear).

// fp32 -> e2m1 nibble, round-to-nearest (values 0,.5,1,1.5,2,3,4,6; clamp at 6)
__device__ __forceinline__ u32 fp4_enc(float x) {
    float y = fabsf(x);
    u32 n = (u32)(y >= 0.25f) + (u32)(y >= 0.75f) + (u32)(y >= 1.25f) +
            (u32)(y >= 1.75f) + (u32)(y >= 2.5f)  + (u32)(y >= 3.5f) +
            (u32)(y >= 5.0f);
    return n | (x < 0.f ? 8u : 0u);
}

__device__ __forceinline__ u16 fp4_pack4(float x, float y, float z, float w) {
    return (u16)(fp4_enc(x) | (fp4_enc(y) << 4) | (fp4_enc(z) << 8) | (fp4_enc(w) << 12));
}

// ---------------- Kernel 1: row norms, fp4 normalize (x32), tiled store, fp32 diag ----------
__global__ __launch_bounds__(256) void norm_kernel(const float4* __restrict__ v,
                                                   const float4* __restrict__ u,
                                                   u16* __restrict__ vn,
                                                   u16* __restrict__ un,
                                                   float* __restrict__ diag) {
    const int wid = threadIdx.x >> 6, lane = threadIdx.x & 63;
    const int row = blockIdx.x * 4 + wid;
    const float4* vr = v + (size_t)row * 192;
    const float4* ur = u + (size_t)row * 192;
    float4 a[3], b[3];
    float sv = 0.f, su = 0.f, sd = 0.f;
#pragma unroll
    for (int c = 0; c < 3; ++c) {
        a[c] = vr[lane + 64 * c];
        b[c] = ur[lane + 64 * c];
        sv += a[c].x * a[c].x + a[c].y * a[c].y + a[c].z * a[c].z + a[c].w * a[c].w;
        su += b[c].x * b[c].x + b[c].y * b[c].y + b[c].z * b[c].z + b[c].w * b[c].w;
        sd += a[c].x * b[c].x + a[c].y * b[c].y + a[c].z * b[c].z + a[c].w * b[c].w;
    }
#pragma unroll
    for (int m = 1; m < 64; m <<= 1) {
        sv += __shfl_xor(sv, m);
        su += __shfl_xor(su, m);
        sd += __shfl_xor(sd, m);
    }
    const float iv = FP4_SCALE / fmaxf(sqrtf(sv), 1e-8f);
    const float iu = FP4_SCALE / fmaxf(sqrtf(su), 1e-8f);
    const int rg = row >> 5, rr = row & 31;
#pragma unroll
    for (int c = 0; c < 3; ++c) {
        u16 pa = fp4_pack4(a[c].x * iv, a[c].y * iv, a[c].z * iv, a[c].w * iv);
        u16 pb = fp4_pack4(b[c].x * iu, b[c].y * iu, b[c].z * iu, b[c].w * iu);
        const int e = lane + 64 * c;   // float4 index within the row (k = 4e..4e+3)
        // u16 index: tile*(1024/2) + h*256 + rr*8 + (e&7)
        const int idx = (rg * 12 + (e >> 4)) * 512 + ((e >> 3) & 1) * 256 + rr * 8 + (e & 7);
        vn[idx] = pa;
        un[idx] = pb;
    }
    if (lane == 0) diag[row] = sd * iv * iu * TAU_INV / (FP4_SCALE * FP4_SCALE);
}

// LDS fragment read: ONE ds_read_b128; fp4 MFMA (cbsz=4/blgp=4) reads only
// v[0:3] of the 8-reg operand; upper half left UNDEF.
__device__ __forceinline__ i32x8 ldsfrag(const u8* p) {
    i32x4 lo = *(const i32x4*)p;
    return __builtin_shufflevector(lo, lo, 0, 1, 2, 3, -1, -1, -1, -1);
}

__device__ __forceinline__ void gload_lds16(const u8* g, u8* l) {
    __builtin_amdgcn_global_load_lds((const __attribute__((address_space(1))) void*)g,
                                     (__attribute__((address_space(3))) void*)l, 16, 0, 0);
}

__device__ __forceinline__ f32x16 mx_mfma4(i32x8 a, i32x8 b, f32x16 c) {
    // cbsz=4 (A fmt E2M1), blgp=4 (B fmt E2M1), scales = 127 -> 1.0
    return __builtin_amdgcn_mfma_scale_f32_32x32x64_f8f6f4(
        a, b, c, 4, 4, 0, 0x7F7F7F7F, 0, 0x7F7F7F7F);
}

// ------- Kernel 2: 256x128 fp4 MX MFMA block tile, 8 waves (512 thr), sized for
//         TWO independent blocks per CU (m114 cross-block overlap): 64x64 wave
//         tile (acc 2x2 = 64 AGPR, ~112 regs <= 128 -> 4 waves/SIMD) and 72 KB
//         LDS (3-slot staging; reduction buffers ALIAS slot 0, dead after t=3).
//         BK=128: 6 steps, 24 staging tiles/step = exactly 3 global_load_lds
//         per wave -> uniform counted s_waitcnt vmcnt(3), depth-2 prefetch.
//         Bijective XCD swizzle (2048 % 8 == 0). -------
__global__ __launch_bounds__(512, 4) void simexp_kernel(const u8* __restrict__ vn,
                                                        const u8* __restrict__ un,
                                                        float* __restrict__ rowP,
                                                        float* __restrict__ colP) {
    // [slot][tile: 0-15 = A rg*2+kb, 16-23 = B rg*2+kb][1024 B]  = 72 KB
    __shared__ __attribute__((aligned(16))) u8 stg[3][24][1024];

    const int tid  = threadIdx.x;
    const int w    = tid >> 6;       // wave 0..7
    const int lane = tid & 63;
    const int l32  = lane & 31;
    const int h    = lane >> 5;
    const int wr = w >> 1, wc = w & 1;   // 4x2 wave grid, 64x64 tile each

    // XCD-contiguous remap (bijective: 2048 % 8 == 0), then 64-block chunks
    // (8rb x 8cb) so one XCD's 4 chunks reuse A/B panels in its private L2.
    const int id0 = blockIdx.x;
    const int id  = (id0 & 7) * 256 + (id0 >> 3);
    const int chunk = id >> 6;
    const int li = id & 63;
    const int rb = (chunk >> 3) * 8 + (li >> 3);   // 0..31  (rows / 256)
    const int cb = (chunk & 7) * 8 + (li & 7);     // 0..63  (cols / 128)

    // staging: wave w owns tiles 3w..3w+2 of the 24 per K-step.
    // tile T<16: A rowgroup rb*8 + (T>>1), kblock-parity T&1;
    // tile T>=16: B rowgroup cb*4 + ((T-16)>>1), parity (T-16)&1.
    // K-step t advances the source by t*2048 B (2 kblocks per step).
    const u8* gt[3];
#pragma unroll
    for (int q = 0; q < 3; ++q) {
        const int T = 3 * w + q;
        const u8* p;
        if (T < 16) {
            p = vn + (size_t)(rb * 8 + (T >> 1)) * 12288 + (size_t)(T & 1) * 1024;
        } else {
            const int S = T - 16;
            p = un + (size_t)(cb * 4 + (S >> 1)) * 12288 + (size_t)(S & 1) * 1024;
        }
        gt[q] = p + (u32)lane * 16;
    }

    f32x16 acc[2][2];
#pragma unroll
    for (int i = 0; i < 2; ++i)
#pragma unroll
        for (int j = 0; j < 2; ++j)
#pragma unroll
            for (int r = 0; r < 16; ++r) acc[i][j][r] = 0.f;

#define STAGE(t)                                                        \
    {                                                                   \
        gload_lds16(gt[0] + (t) * 2048, &stg[(t) % 3][3 * w + 0][0]);   \
        gload_lds16(gt[1] + (t) * 2048, &stg[(t) % 3][3 * w + 1][0]);   \
        gload_lds16(gt[2] + (t) * 2048, &stg[(t) % 3][3 * w + 2][0]);   \
    }

    // prologue: prefetch K-steps 0 and 1 (6 loads out; wait own step-0 3 done)
    STAGE(0)
    STAGE(1)
    asm volatile("s_waitcnt vmcnt(3)\n\ts_barrier" ::: "memory");

#pragma unroll
    for (int t = 0; t < 6; ++t) {
        if (t + 2 < 6) STAGE(t + 2)          // prefetch depth 2 into slot (t+2)%3
        const u8* s = &stg[t % 3][0][0] + (u32)lane * 16;
#pragma unroll
        for (int kk = 0; kk < 2; ++kk) {
            i32x8 fa0 = ldsfrag(s + (((wr * 2 + 0) * 2 + kk)) * 1024);
            i32x8 fa1 = ldsfrag(s + (((wr * 2 + 1) * 2 + kk)) * 1024);
            i32x8 fb0 = ldsfrag(s + ((16 + (wc * 2 + 0) * 2 + kk)) * 1024);
            i32x8 fb1 = ldsfrag(s + ((16 + (wc * 2 + 1) * 2 + kk)) * 1024);
            __builtin_amdgcn_s_setprio(1);
            acc[0][0] = mx_mfma4(fa0, fb0, acc[0][0]);
            acc[1][0] = mx_mfma4(fa1, fb0, acc[1][0]);
            acc[0][1] = mx_mfma4(fa0, fb1, acc[0][1]);
            acc[1][1] = mx_mfma4(fa1, fb1, acc[1][1]);
            __builtin_amdgcn_s_setprio(0);
        }
        // own prefetch for step t+1 must be done (3 newest, for t+2, may fly),
        // then barrier so ALL waves' tiles for t+1 are visible. t=4 drains its
        // last prefetch (step 5). No sync after t=5 (stg slots never re-staged;
        // epilogue has its own __syncthreads before cross-wave LDS reads).
        if (t < 4)       asm volatile("s_waitcnt vmcnt(3)\n\ts_barrier" ::: "memory");
        else if (t == 4) asm volatile("s_waitcnt vmcnt(0)\n\ts_barrier" ::: "memory");
    }
#undef STAGE

    // ---------------- Epilogue (R2-verified fold-reduce) ----------------
    // 32x32 C/D layout: col = lane&31, row = (reg&3) + 8*(reg>>2) + 4*h.
    // Reduction buffers alias stg slot 0 (dead since the t=3 end-of-step
    // barrier): rowRed[2][256] floats then colRed[4][128] floats (4 KB total).
    float* rowRed = (float*)&stg[0][0][0];
    float* colRed = rowRed + 512;

    f32x2 val2[16];            // [i*8 + r/2] row-sum partials (pairs of regs)
    f32x2 cacc2[2];            // [j] col-sum partials
#pragma unroll
    for (int p = 0; p < 16; ++p) { val2[p].x = 0.f; val2[p].y = 0.f; }
    cacc2[0].x = 0.f; cacc2[0].y = 0.f;
    cacc2[1].x = 0.f; cacc2[1].y = 0.f;
#pragma unroll
    for (int i = 0; i < 2; ++i)
#pragma unroll
        for (int j = 0; j < 2; ++j)
#pragma unroll
            for (int r = 0; r < 16; r += 2) {
                f32x2 a;
                a.x = acc[i][j][r];
                a.y = acc[i][j][r + 1];
                f32x2 t = a * SCHRAU_K1 + SCHRAU_K2;   // v_pk_fma_f32
                f32x2 e;
                e.x = __int_as_float((int)t.x);
                e.y = __int_as_float((int)t.y);
                val2[i * 8 + (r >> 1)] += e;
                cacc2[j] += e;
            }

    // Fold-reduce over the 32 columns: each lane ends owning one row total.
#pragma unroll
    for (int m = 16; m >= 2; m >>= 1) {
        const int n = m >> 1;
        const bool hi = (l32 & m) != 0;
#pragma unroll
        for (int p = 0; p < n; ++p) {
            f32x2 a = val2[p], b = val2[p + n];
            f32x2 x, y;
            x.x = hi ? b.x : a.x;  x.y = hi ? b.y : a.y;
            y.x = hi ? a.x : b.x;  y.y = hi ? a.y : b.y;
            f32x2 s;
            s.x = __shfl_xor(y.x, m);
            s.y = __shfl_xor(y.y, m);
            val2[p] = x + s;
        }
    }
    {   // lanes l and l^1 hold complementary 16-lane partials of the same pair
        f32x2 s;
        s.x = __shfl_xor(val2[0].x, 1);
        s.y = __shfl_xor(val2[0].y, 1);
        val2[0] += s;
    }
    {
        const int q = (l32 >> 1) & 15;
        const int tt = 2 * q + (l32 & 1);
        const int i2 = tt >> 4, r2 = tt & 15;
        const int rbase = i2 * 32 + (r2 & 3) + 8 * (r2 >> 2) + 4 * h;
        rowRed[wc * 256 + wr * 64 + rbase] = (l32 & 1) ? val2[0].y : val2[0].x;
    }
    {
        float c0 = cacc2[0].x + cacc2[0].y;
        float c1 = cacc2[1].x + cacc2[1].y;
        c0 += __shfl_xor(c0, 32);
        c1 += __shfl_xor(c1, 32);
        if (h == 0) {
            colRed[wr * 128 + wc * 64 + l32]      = c0;
            colRed[wr * 128 + wc * 64 + 32 + l32] = c1;
        }
    }
    __syncthreads();
    if (tid < 256) {
        rowP[(size_t)cb * B_SZ + rb * 256 + tid] = rowRed[tid] + rowRed[256 + tid];
    } else if (tid < 384) {
        const int t = tid - 256;
        colP[(size_t)rb * B_SZ + cb * 128 + t] =
            colRed[t] + colRed[128 + t] + colRed[256 + t] + colRed[384 + t];
    }
}

// ---------------- Kernel 3: reduce partials, log, subtract diag, mean ----------------
__global__ __launch_bounds__(256) void finalize_kernel(const float* __restrict__ rowP,
                                                       const float* __restrict__ colP,
                                                       const float* __restrict__ diag,
                                                       float* __restrict__ out) {
    const int i = blockIdx.x * 256 + threadIdx.x;
    float rs = 0.f, cs = 0.f;
#pragma unroll 8
    for (int p = 0; p < 64; ++p) rs += rowP[(size_t)p * B_SZ + i];
#pragma unroll 8
    for (int p = 0; p < 32; ++p) cs += colP[(size_t)p * B_SZ + i];
    float contrib = (0.75f * logf(rs) + 0.25f * logf(cs) - diag[i]) * (1.0f / (float)B_SZ);
#pragma unroll
    for (int m = 1; m < 64; m <<= 1) contrib += __shfl_xor(contrib, m);
    __shared__ float red[4];
    const int wid = threadIdx.x >> 6, lane = threadIdx.x & 63;
    if (lane == 0) red[wid] = contrib;
    __syncthreads();
    if (threadIdx.x == 0) atomicAdd(out, red[0] + red[1] + red[2] + red[3]);
}

extern "C" void kernel_launch(void* const* d_in, const int* in_sizes, int n_in,
                              void* d_out, int out_size, void* d_ws, size_t ws_size,
                              hipStream_t stream) {
    const float* v = (const float*)d_in[0];
    const float* u = (const float*)d_in[1];
    char* ws = (char*)d_ws;
    // workspace layout (~9.5 MB)
    u16* vn4   = (u16*)(ws);                    // 8192*384 B  = 3,145,728
    u16* un4   = (u16*)(ws + 3145728);          // 3,145,728
    float* dg  = (float*)(ws + 6291456);        // 8192*4      = 32,768
    float* rwp = (float*)(ws + 6324224);        // 64*8192*4   = 2,097,152
    float* clp = (float*)(ws + 8421376);        // 32*8192*4   = 1,048,576
    float* out = (float*)d_out;

    hipMemsetAsync(out, 0, sizeof(float), stream);
    hipLaunchKernelGGL(norm_kernel, dim3(2048), dim3(256), 0, stream,
                       (const float4*)v, (const float4*)u, vn4, un4, dg);
    hipLaunchKernelGGL(simexp_kernel, dim3(2048), dim3(512), 0, stream,
                       (const u8*)vn4, (const u8*)un4, rwp, clp);
    hipLaunchKernelGGL(finalize_kernel, dim3(B_SZ / 256), dim3(256), 0, stream, rwp, clp, dg, out);
}